// Round 2
// baseline (187.152 us; speedup 1.0000x reference)
//
#include <hip/hip_runtime.h>
#include <math.h>

constexpr int NSUP = 3072;            // B*S images
constexpr float EPSF = 1e-5f;

// Workspace layout (float offsets)
constexpr int WS_W1B  = 0;            // bf16 [kt2][h2][quad4][col16][8] conv1 composite -> 1024 f
constexpr int WS_B1   = 1024;         // fp32 32
constexpr int WS_W2B  = 1056;         // bf16 [tap9][h2][quad4][col16][8] = 9216 ush = 4608 f
constexpr int WS_W3B  = 5664;         // same
constexpr int WS_W4B  = 10272;        // bf16 [tap9][ic32] = 288 ush = 144 f
constexpr int WS_B4   = 10416;        // fp32 1 (+pad)
constexpr int WS_B2   = 10420;        // fp32 32
constexpr int WS_B3   = 10452;        // fp32 32
constexpr int WS_HW1  = 10484;        // bf16 [64][72] = 4608 ush = 2304 f
constexpr int WS_HW2  = 12788;
constexpr int WS_HRQ  = 15092;
constexpr int WS_HROT = 17396;        // ro^T
constexpr int WS_PART = 19700;        // [512] loss, [512] correct
constexpr int WS_FEATS= 20724;        // 4096*64 f32

using short8 = __attribute__((ext_vector_type(8))) short;
using f32x4  = __attribute__((ext_vector_type(4))) float;

// Branchless gelu: 0.5x(1+erf(x/sqrt2)), erf via A&S 7.1.26 (|err|<=1.5e-7).
__device__ __forceinline__ float gelu_f(float x) {
    float z  = fabsf(x) * 0.70710678118654752440f;
    float t  = __builtin_amdgcn_rcpf(__builtin_fmaf(0.3275911f, z, 1.0f));
    float p  = t * __builtin_fmaf(t,
                 __builtin_fmaf(t,
                   __builtin_fmaf(t,
                     __builtin_fmaf(t, 1.061405429f, -1.453152027f),
                     1.421413741f),
                   -0.284496736f),
                 0.254829592f);
    float e  = __expf(-z * z);
    float er = __builtin_fmaf(-p, e, 1.0f);          // erf(|x|/sqrt2)
    float s  = copysignf(er, x);
    return 0.5f * x * (1.0f + s);
}
__device__ __forceinline__ unsigned short f2bf(float f) {
    unsigned u = __float_as_uint(f);
    return (unsigned short)((u + 0x7FFFu + ((u >> 16) & 1u)) >> 16);
}
__device__ __forceinline__ float bflo(unsigned u) { return __uint_as_float(u << 16); }
__device__ __forceinline__ float bfhi(unsigned u) { return __uint_as_float(u & 0xffff0000u); }

// ---------------------------------------------------------------------------
// Precompute: fold BN; emit bf16 MFMA layouts for all conv + head weights.
// Conv weights are emitted in [..][h][quad][col][8ch] order so that a wave's
// 64-lane ds_read_b128 of a B-fragment is one contiguous 1024B block
// (conflict-free) instead of stride-64B (8-way bank conflict).
// ---------------------------------------------------------------------------
__global__ void __launch_bounds__(256) precompute_kernel(
    const float* __restrict__ c1w, const float* __restrict__ c1b, const float* __restrict__ bn1,
    const float* __restrict__ c2w, const float* __restrict__ c2b, const float* __restrict__ bn2,
    const float* __restrict__ c3w, const float* __restrict__ c3b, const float* __restrict__ bn3,
    const float* __restrict__ c4w, const float* __restrict__ c4b, const float* __restrict__ bn4,
    const float* __restrict__ w1, const float* __restrict__ w2,
    const float* __restrict__ rq, const float* __restrict__ ro,
    float* __restrict__ ws)
{
    const int gid = blockIdx.x * 256 + threadIdx.x;
    const int gsz = gridDim.x * 256;

    // conv1 composite B: v = (((kt*2+h)*4+qd)*16+col)*8 + c8
    // tap = kt*32 + qd*8 + c8 (0..35, zero-padded), oc = h*16+col
    unsigned short* w1b = (unsigned short*)(ws + WS_W1B);
    for (int v = gid; v < 2048; v += gsz) {
        int c8 = v & 7, colx = (v >> 3) & 15, qd = (v >> 7) & 3, hh = (v >> 9) & 1, kt = v >> 10;
        int tap = kt * 32 + qd * 8 + c8;
        int oc = hh * 16 + colx;
        unsigned short o = 0;
        if (tap < 36) {
            int tt = tap / 6, s = tap - tt * 6;
            float sum = 0.f;
            for (int di = 0; di < 3; ++di) {
                int a = tt - di; if (a < 0 || a > 3) continue;
                for (int dj = 0; dj < 3; ++dj) {
                    int bb = s - dj; if (bb < 0 || bb > 3) continue;
                    sum += c1w[oc * 9 + di * 3 + dj];
                }
            }
            float sc1 = bn1[oc] * rsqrtf(bn1[96 + oc] + EPSF);
            o = f2bf(sum * sc1 * (1.0f / 16.0f));
        }
        w1b[v] = o;
    }
    for (int c = gid; c < 32; c += gsz) {
        float sc1 = bn1[c] * rsqrtf(bn1[96 + c] + EPSF);
        ws[WS_B1 + c] = (c1b[c] - bn1[64 + c]) * sc1 + bn1[32 + c];
        float sc2 = bn2[c] * rsqrtf(bn2[96 + c] + EPSF);
        ws[WS_B2 + c] = (c2b[c] - bn2[64 + c]) * sc2 + bn2[32 + c];
        float sc3 = bn3[c] * rsqrtf(bn3[96 + c] + EPSF);
        ws[WS_B3 + c] = (c3b[c] - bn3[64 + c]) * sc3 + bn3[32 + c];
    }
    // conv2/3: v = (((tap*2+h)*4+qd)*16+col)*8 + c8 ; oc=h*16+col, ic=qd*8+c8
    unsigned short* w2b = (unsigned short*)(ws + WS_W2B);
    unsigned short* w3b = (unsigned short*)(ws + WS_W3B);
    for (int v = gid; v < 9216; v += gsz) {
        int c8 = v & 7, colx = (v >> 3) & 15, qd = (v >> 7) & 3, hh = (v >> 9) & 1, tap = v >> 10;
        int oc = hh * 16 + colx;
        int ic = qd * 8 + c8;
        float sc2 = bn2[oc] * rsqrtf(bn2[96 + oc] + EPSF);
        float sc3 = bn3[oc] * rsqrtf(bn3[96 + oc] + EPSF);
        w2b[v] = f2bf(c2w[oc * 288 + ic * 9 + tap] * sc2);
        w3b[v] = f2bf(c3w[oc * 288 + ic * 9 + tap] * sc3);
    }
    {
        unsigned short* w4b = (unsigned short*)(ws + WS_W4B);
        float sc4 = bn4[0] * rsqrtf(bn4[3] + EPSF);
        for (int v = gid; v < 288; v += gsz) {
            int tap = v >> 5, ic = v & 31;
            w4b[v] = f2bf(c4w[ic * 9 + tap] * sc4);
        }
        if (gid == 0) ws[WS_B4] = (c4b[0] - bn4[2]) * sc4 + bn4[1];
    }
    // head weights bf16 [64][72]
    unsigned short* hw1 = (unsigned short*)(ws + WS_HW1);
    unsigned short* hw2 = (unsigned short*)(ws + WS_HW2);
    unsigned short* hrq = (unsigned short*)(ws + WS_HRQ);
    unsigned short* hro = (unsigned short*)(ws + WS_HROT);
    for (int v = gid; v < 4608; v += gsz) {
        int e = v / 72, d = v - e * 72;
        unsigned short a = 0, b = 0, c = 0, r = 0;
        if (d < 64) {
            a = f2bf(w1[e * 64 + d]);
            b = f2bf(w2[e * 64 + d]);
            c = f2bf(rq[e * 64 + d]);
            r = f2bf(ro[d * 64 + e]);
        }
        hw1[v] = a; hw2[v] = b; hrq[v] = c; hro[v] = r;
    }
}

// ---------------------------------------------------------------------------
// feats: 1024 threads = 16 waves = 8 images, 2 waves per image (halved
// per-wave critical path). Act buffer per image: chunk-major
// [4 quad-chunk][100 px][8 ch] bf16 -> conflict-free ds_read_b128 A-fragments
// and ~free epilogue u16 writes. In-place conv read/write phases are
// barrier-separated (wave halves exchange halo rows).
// ---------------------------------------------------------------------------
__device__ __forceinline__ void conv32_mfma(const unsigned short* __restrict__ A,
                                            const unsigned short* __restrict__ W,
                                            int col, int quad, int half,
                                            f32x4 (&acc)[2][2])
{
    int ab[2];
    #pragma unroll
    for (int m = 0; m < 2; ++m) {
        int px = (half * 2 + m) * 16 + col;
        ab[m] = quad * 800 + ((px >> 3) * 10 + (px & 7)) * 8;
        acc[m][0] = (f32x4){0,0,0,0};
        acc[m][1] = (f32x4){0,0,0,0};
    }
    #pragma unroll
    for (int dr = 0; dr < 3; ++dr)
        #pragma unroll
        for (int dc = 0; dc < 3; ++dc) {
            int tap = dr * 3 + dc;
            short8 b0 = *(const short8*)(W + (((tap * 2 + 0) * 4 + quad) * 16 + col) * 8);
            short8 b1 = *(const short8*)(W + (((tap * 2 + 1) * 4 + quad) * 16 + col) * 8);
            #pragma unroll
            for (int m = 0; m < 2; ++m) {
                short8 a = *(const short8*)(A + ab[m] + (dr * 10 + dc) * 8);
                acc[m][0] = __builtin_amdgcn_mfma_f32_16x16x32_bf16(a, b0, acc[m][0], 0, 0, 0);
                acc[m][1] = __builtin_amdgcn_mfma_f32_16x16x32_bf16(a, b1, acc[m][1], 0, 0, 0);
            }
        }
}

__device__ __forceinline__ void conv_store(unsigned short* __restrict__ A,
                                           const f32x4 (&acc)[2][2],
                                           float bi0, float bi1, int col, int quad, int half)
{
    #pragma unroll
    for (int m = 0; m < 2; ++m)
        #pragma unroll
        for (int reg = 0; reg < 4; ++reg) {
            int px = (half * 2 + m) * 16 + quad * 4 + reg;
            int P = ((px >> 3) + 1) * 10 + (px & 7) + 1;
            A[(col >> 3) * 800 + P * 8 + (col & 7)]       = f2bf(gelu_f(acc[m][0][reg] + bi0));
            A[(2 + (col >> 3)) * 800 + P * 8 + (col & 7)] = f2bf(gelu_f(acc[m][1][reg] + bi1));
        }
}

__global__ void __launch_bounds__(1024, 8) feats_kernel(
    const float* __restrict__ sxs, const float* __restrict__ qxs,
    const float* __restrict__ lin_w, const float* __restrict__ ws,
    float* __restrict__ feats)
{
    __shared__ __align__(16) unsigned short sAct[8][3200];
    __shared__ __align__(16) unsigned short sWB[9216];
    __shared__ __align__(16) unsigned short sW4[288];
    __shared__ __align__(16) float sh4[8][64];

    const int t    = threadIdx.x;
    const int wv   = t >> 6;
    const int half = wv & 1;          // which half of the image this wave owns
    const int iw   = wv >> 1;         // image index within block
    const int lane = t & 63;
    const int col  = lane & 15;
    const int quad = lane >> 4;
    const int n    = blockIdx.x * 8 + iw;

    unsigned short* A = sAct[iw];

    // Bias prefetch (removes post-barrier global latency from epilogues).
    float bi1a = ws[WS_B1 + col],      bi1b = ws[WS_B1 + 16 + col];
    float bi2a = ws[WS_B2 + col],      bi2b = ws[WS_B2 + 16 + col];
    float bi3a = ws[WS_B3 + col],      bi3b = ws[WS_B3 + 16 + col];
    float b4   = ws[WS_B4];

    // Prefetch W2 into registers (1152 uint4 over 1024 threads).
    const uint4* w2v = (const uint4*)(ws + WS_W2B);
    uint4 pwA = w2v[t];
    uint4 pwB = {0, 0, 0, 0};
    if (t < 128) pwB = w2v[t + 1024];

    // Stage this image (2 waves cooperatively), converted to bf16, linear.
    {
        const float* img = (n < NSUP) ? (sxs + (size_t)n * 784) : (qxs + (size_t)(n - NSUP) * 784);
        const float4* sv = (const float4*)img;
        #pragma unroll
        for (int j = 0; j < 2; ++j) {
            int idx = j * 128 + half * 64 + lane;
            if (idx < 196) {
                float4 v = sv[idx];
                ushort4 o = { f2bf(v.x), f2bf(v.y), f2bf(v.z), f2bf(v.w) };
                *(ushort4*)(A + idx * 4) = o;
            }
        }
    }
    if (t < 256) ((uint4*)sWB)[t] = ((const uint4*)(ws + WS_W1B))[t];
    __syncthreads();                                   // S0

    // ---- conv1 MFMA: 64x32xK36 GEMM, this wave's 2 row-tiles ----
    f32x4 acc[2][2];
    {
        int ttj[8], ssj[8];
        #pragma unroll
        for (int j = 0; j < 8; ++j) {
            int k = quad * 8 + j;
            ttj[j] = k / 6; ssj[j] = k - ttj[j] * 6;
        }
        short8 b00 = *(const short8*)(sWB + ((0 * 4 + quad) * 16 + col) * 8);  // kt0 h0
        short8 b01 = *(const short8*)(sWB + ((1 * 4 + quad) * 16 + col) * 8);  // kt0 h1
        short8 b10 = *(const short8*)(sWB + ((2 * 4 + quad) * 16 + col) * 8);  // kt1 h0
        short8 b11 = *(const short8*)(sWB + ((3 * 4 + quad) * 16 + col) * 8);  // kt1 h1

        #pragma unroll
        for (int m = 0; m < 2; ++m) {
            acc[m][0] = (f32x4){0,0,0,0};
            acc[m][1] = (f32x4){0,0,0,0};
            int px = (half * 2 + m) * 16 + col;
            int sr = (((px >> 3) * 7) >> 1) - 1;
            int sc = (((px & 7) * 7) >> 1) - 1;
            short8 a0;
            #pragma unroll
            for (int j = 0; j < 8; ++j) {
                int rr = sr + ttj[j], cc = sc + ssj[j];
                bool ok = ((unsigned)rr < 28u) && ((unsigned)cc < 28u);
                int off = ok ? (rr * 28 + cc) : 0;
                unsigned short hv = A[off];
                a0[j] = ok ? (short)hv : (short)0;
            }
            acc[m][0] = __builtin_amdgcn_mfma_f32_16x16x32_bf16(a0, b00, acc[m][0], 0, 0, 0);
            acc[m][1] = __builtin_amdgcn_mfma_f32_16x16x32_bf16(a0, b01, acc[m][1], 0, 0, 0);
            short8 a1 = {0,0,0,0,0,0,0,0};
            if (quad == 0) {
                #pragma unroll
                for (int j = 0; j < 4; ++j) {          // k=32..35 -> tt=5, ss=2+j
                    int rr = sr + 5, cc = sc + 2 + j;
                    bool ok = ((unsigned)rr < 28u) && ((unsigned)cc < 28u);
                    int off = ok ? (rr * 28 + cc) : 0;
                    unsigned short hv = A[off];
                    a1[j] = ok ? (short)hv : (short)0;
                }
            }
            acc[m][0] = __builtin_amdgcn_mfma_f32_16x16x32_bf16(a1, b10, acc[m][0], 0, 0, 0);
            acc[m][1] = __builtin_amdgcn_mfma_f32_16x16x32_bf16(a1, b11, acc[m][1], 0, 0, 0);
        }
    }
    __syncthreads();                                   // S1 (raw reads done, W1 reads done)

    // ---- conv1 epilogue: halo zero + interior write; commit W2; stage W4; prefetch W3 ----
    {
        uint4 z4 = {0, 0, 0, 0};
        int t2 = half * 64 + lane;                     // 0..127 per image
        #pragma unroll
        for (int it = 0; it < 2; ++it) {
            int h = t2 + it * 128;
            if (h < 144) {                             // 36 halo pixels x 4 chunks
                int pi = h >> 2, ch = h & 3;
                int P;
                if (pi < 10)      P = pi;                              // row 0
                else if (pi < 20) P = 90 + (pi - 10);                  // row 9
                else { int r = 1 + ((pi - 20) >> 1); P = r * 10 + ((pi - 20) & 1) * 9; }
                ((uint4*)A)[ch * 100 + P] = z4;
            }
        }
        conv_store(A, acc, bi1a, bi1b, col, quad, half);

        ((uint4*)sWB)[t] = pwA;
        if (t < 128) ((uint4*)sWB)[t + 1024] = pwB;
        if (t < 36)  ((uint4*)sW4)[t] = ((const uint4*)(ws + WS_W4B))[t];
        const uint4* w3v = (const uint4*)(ws + WS_W3B);
        pwA = w3v[t];
        if (t < 128) pwB = w3v[t + 1024];
    }
    __syncthreads();                                   // S2

    // ---- conv2 ----
    conv32_mfma(A, sWB, col, quad, half, acc);
    __syncthreads();                                   // S3 (all reads done before in-place write)
    conv_store(A, acc, bi2a, bi2b, col, quad, half);
    ((uint4*)sWB)[t] = pwA;                            // commit W3 (conv2 reads finished)
    if (t < 128) ((uint4*)sWB)[t + 1024] = pwB;
    __syncthreads();                                   // S4

    // ---- conv3 ----
    conv32_mfma(A, sWB, col, quad, half, acc);
    __syncthreads();                                   // S5
    conv_store(A, acc, bi3a, bi3b, col, quad, half);
    __syncthreads();                                   // S6

    // ---- conv4 (32->1) via broadcast-B MFMA ----
    {
        f32x4 acc4[2];
        int ab[2];
        #pragma unroll
        for (int m = 0; m < 2; ++m) {
            int px = (half * 2 + m) * 16 + col;
            ab[m] = quad * 800 + ((px >> 3) * 10 + (px & 7)) * 8;
            acc4[m] = (f32x4){0,0,0,0};
        }
        #pragma unroll
        for (int dr = 0; dr < 3; ++dr)
            #pragma unroll
            for (int dc = 0; dc < 3; ++dc) {
                int tap = dr * 3 + dc;
                short8 b = *(const short8*)(sW4 + tap * 32 + quad * 8);
                #pragma unroll
                for (int m = 0; m < 2; ++m) {
                    short8 a = *(const short8*)(A + ab[m] + (dr * 10 + dc) * 8);
                    acc4[m] = __builtin_amdgcn_mfma_f32_16x16x32_bf16(a, b, acc4[m], 0, 0, 0);
                }
            }
        if (col < 2) {
            f32x4 v = (col == 0) ? acc4[0] : acc4[1];
            #pragma unroll
            for (int reg = 0; reg < 4; ++reg)
                sh4[iw][(half * 2 + col) * 16 + quad * 4 + reg] = gelu_f(v[reg] + b4);
        }
    }
    __syncthreads();                                   // S7 (sh4 complete across wave pair)

    // ---- Linear 64x64 fp32: each wave produces 32 of the 64 outputs ----
    {
        int o = half * 32 + (lane & 31);
        const float4* lw = (const float4*)(lin_w + (size_t)o * 64);
        const float4* hp = (const float4*)sh4[iw];
        float acc2 = 0.f;
        #pragma unroll
        for (int j = 0; j < 16; ++j) {
            float4 w = lw[j], h = hp[j];
            acc2 += w.x * h.x + w.y * h.y + w.z * h.z + w.w * h.w;
        }
        if (lane < 32) feats[n * 64 + o] = acc2;
    }
}

// ---------------------------------------------------------------------------
// head: 1 batch element per block, 256 threads, bf16 MFMA GEMMs.
// ---------------------------------------------------------------------------
__device__ __forceinline__ void head_gemm(const unsigned short* __restrict__ Ab,
                                          const unsigned short* __restrict__ Bw,
                                          int col, int quad, int wvid, f32x4 res[2])
{
    #pragma unroll
    for (int u = 0; u < 2; ++u) {
        int tau = wvid + u * 4;
        int mt = tau & 1, nt = tau >> 1;
        f32x4 acc = {0, 0, 0, 0};
        #pragma unroll
        for (int kt = 0; kt < 2; ++kt) {
            short8 a = *(const short8*)(Ab + (mt * 16 + col) * 72 + kt * 32 + quad * 8);
            short8 b = *(const short8*)(Bw + (nt * 16 + col) * 72 + kt * 32 + quad * 8);
            acc = __builtin_amdgcn_mfma_f32_16x16x32_bf16(a, b, acc, 0, 0, 0);
        }
        res[u] = acc;
    }
}

__global__ void __launch_bounds__(256, 2) head_kernel(
    const float* __restrict__ emb, const float* __restrict__ tags,
    const float* __restrict__ rk, const float* __restrict__ rv,
    const float* __restrict__ lnw, const float* __restrict__ lnb,
    const int* __restrict__ sys, const int* __restrict__ qys,
    const float* __restrict__ ws, const float* __restrict__ feats,
    float* __restrict__ part)
{
    __shared__ __align__(16) unsigned short sW1B[4608], sW2B[4608], sRQB[4608], sROT[4608];
    __shared__ __align__(16) unsigned short bufA[2304], bufB[2304];
    __shared__ __align__(16) float sXf[1536];
    __shared__ __align__(16) float sRK[1024], sRV[1024];
    __shared__ __align__(16) float s_xq[128], s_ah[128], s_yp[128];
    __shared__ float s_t1[12], s_t2[12], s_mu[24], s_rs[24], s_lg[4];

    const int t    = threadIdx.x;
    const int b    = blockIdx.x;
    const int wvid = t >> 6;
    const int col  = t & 15;
    const int quad = (t >> 4) & 3;

    ((float4*)sRK)[t] = ((const float4*)rk)[t];
    ((float4*)sRV)[t] = ((const float4*)rv)[t];
    for (int i = t; i < 576; i += 256) {      // 4608 ush = 576 uint4 each
        ((uint4*)sW1B)[i] = ((const uint4*)(ws + WS_HW1))[i];
        ((uint4*)sW2B)[i] = ((const uint4*)(ws + WS_HW2))[i];
        ((uint4*)sRQB)[i] = ((const uint4*)(ws + WS_HRQ))[i];
        ((uint4*)sROT)[i] = ((const uint4*)(ws + WS_HROT))[i];
    }
    if (t < 72) {   // zero pad rows 24..31 (576 ush = 72 uint4 each)
        uint4 z = {0, 0, 0, 0};
        ((uint4*)(bufA + 1728))[t] = z;
        ((uint4*)(bufB + 1728))[t] = z;
    }
    // tokens (fp32 + bf16)
    for (int idx = t; idx < 1536; idx += 256) {
        int k = idx >> 6, e = idx & 63;
        int s = k >> 2, tg = k & 3;
        int cls = sys[b * 6 + s];
        float v = feats[(b * 6 + s) * 64 + e] + emb[cls * 64 + e] + tags[tg * 64 + e];
        sXf[idx] = v;
        bufA[k * 72 + e] = f2bf(v);
    }
    __syncthreads();

    f32x4 r[2];
    // GEMM1: ah = gelu(X @ w1^T) -> bufB
    head_gemm(bufA, sW1B, col, quad, wvid, r);
    #pragma unroll
    for (int u = 0; u < 2; ++u) {
        int tau = wvid + u * 4, mt = tau & 1, nt = tau >> 1;
        #pragma unroll
        for (int reg = 0; reg < 4; ++reg) {
            int row = mt * 16 + quad * 4 + reg;
            if (row < 24) bufB[row * 72 + nt * 16 + col] = f2bf(gelu_f(r[u][reg]));
        }
    }
    __syncthreads();
    // GEMM2: q = ah @ w2^T -> bufA
    head_gemm(bufB, sW2B, col, quad, wvid, r);
    #pragma unroll
    for (int u = 0; u < 2; ++u) {
        int tau = wvid + u * 4, mt = tau & 1, nt = tau >> 1;
        #pragma unroll
        for (int reg = 0; reg < 4; ++reg) {
            int row = mt * 16 + quad * 4 + reg;
            if (row < 24) bufA[row * 72 + nt * 16 + col] = f2bf(r[u][reg]);
        }
    }
    __syncthreads();
    // GEMM3: qh = q @ rq^T -> bufB
    head_gemm(bufA, sRQB, col, quad, wvid, r);
    #pragma unroll
    for (int u = 0; u < 2; ++u) {
        int tau = wvid + u * 4, mt = tau & 1, nt = tau >> 1;
        #pragma unroll
        for (int reg = 0; reg < 4; ++reg) {
            int row = mt * 16 + quad * 4 + reg;
            if (row < 24) bufB[row * 72 + nt * 16 + col] = f2bf(r[u][reg]);
        }
    }
    __syncthreads();

    // attention over 16 slots per (k, head) -> lor bf16 in bufA
    if (t < 96) {
        int k = t >> 2, nn = t & 3;
        const unsigned short* qp = bufB + k * 72 + nn * 16;
        uint4 u0 = *(const uint4*)(qp);
        uint4 u1 = *(const uint4*)(qp + 8);
        float qv[16];
        qv[0]=bflo(u0.x); qv[1]=bfhi(u0.x); qv[2]=bflo(u0.y); qv[3]=bfhi(u0.y);
        qv[4]=bflo(u0.z); qv[5]=bfhi(u0.z); qv[6]=bflo(u0.w); qv[7]=bfhi(u0.w);
        qv[8]=bflo(u1.x); qv[9]=bfhi(u1.x); qv[10]=bflo(u1.y); qv[11]=bfhi(u1.y);
        qv[12]=bflo(u1.z); qv[13]=bfhi(u1.z); qv[14]=bflo(u1.w); qv[15]=bfhi(u1.w);
        float sc[16]; float mx = -1e30f;
        #pragma unroll
        for (int rr = 0; rr < 16; ++rr) {
            const float* kp = sRK + rr * 64 + nn * 16;
            float d = 0.f;
            #pragma unroll
            for (int h = 0; h < 16; ++h) d += qv[h] * kp[h];
            d *= 0.25f;
            sc[rr] = d; mx = fmaxf(mx, d);
        }
        float sum = 0.f;
        #pragma unroll
        for (int rr = 0; rr < 16; ++rr) { sc[rr] = __expf(sc[rr] - mx); sum += sc[rr]; }
        float inv = 1.0f / sum;
        float o[16];
        #pragma unroll
        for (int h = 0; h < 16; ++h) o[h] = 0.f;
        #pragma unroll
        for (int rr = 0; rr < 16; ++rr) {
            const float* vp = sRV + rr * 64 + nn * 16;
            float p = sc[rr];
            #pragma unroll
            for (int h = 0; h < 16; ++h) o[h] += p * vp[h];
        }
        unsigned short* op = bufA + k * 72 + nn * 16;
        #pragma unroll
        for (int h = 0; h < 16; ++h) op[h] = f2bf(o[h] * inv);
    }
    __syncthreads();

    // GEMM4: z = x + lor @ ro -> sXf (in-place)
    head_gemm(bufA, sROT, col, quad, wvid, r);
    #pragma unroll
    for (int u = 0; u < 2; ++u) {
        int tau = wvid + u * 4, mt = tau & 1, nt = tau >> 1;
        #pragma unroll
        for (int reg = 0; reg < 4; ++reg) {
            int row = mt * 16 + quad * 4 + reg;
            if (row < 24) {
                int idx = row * 64 + nt * 16 + col;
                sXf[idx] = sXf[idx] + r[u][reg];
            }
        }
    }
    __syncthreads();

    // LayerNorm stats
    if (t < 24) {
        const float4* zp = (const float4*)(sXf + t * 64);
        float sx_ = 0.f;
        #pragma unroll
        for (int j = 0; j < 16; ++j) {
            float4 v = zp[(j + t) & 15];
            sx_ += v.x + v.y + v.z + v.w;
        }
        float mu = sx_ * (1.0f / 64.0f);
        float vv = 0.f;
        #pragma unroll
        for (int j = 0; j < 16; ++j) {
            float4 v = zp[(j + t) & 15];
            float d0 = v.x - mu, d1 = v.y - mu, d2 = v.z - mu, d3 = v.w - mu;
            vv += d0*d0 + d1*d1 + d2*d2 + d3*d3;
        }
        s_mu[t] = mu;
        s_rs[t] = 1.0f / sqrtf(vv * (1.0f / 64.0f) + EPSF);
    }
    __syncthreads();
    // normalize -> lors bf16 in bufB ; xq staged in parallel
    for (int idx = t; idx < 1536; idx += 256) {
        int k = idx >> 6, e = idx & 63;
        float v = (sXf[idx] - s_mu[k]) * s_rs[k] * lnw[e] + lnb[e];
        bufB[k * 72 + e] = f2bf(v);
    }
    if (t < 128) {
        int q = t >> 6, e = t & 63;
        s_xq[t] = feats[(NSUP + b * 2 + q) * 64 + e] + tags[256 + e];
    }
    __syncthreads();

    // t1[q][s] = r1s[s] . xq[q]
    if (t < 12) {
        int q = t / 6, s = t - q * 6;
        const uint4* rp = (const uint4*)(bufB + (s * 4 + 1) * 72);
        const float* xp = s_xq + q * 64;
        float d = 0.f;
        #pragma unroll
        for (int j = 0; j < 8; ++j) {
            uint4 u = rp[j];
            const float* x = xp + j * 8;
            d += bflo(u.x)*x[0] + bfhi(u.x)*x[1] + bflo(u.y)*x[2] + bfhi(u.y)*x[3]
               + bflo(u.z)*x[4] + bfhi(u.z)*x[5] + bflo(u.w)*x[6] + bfhi(u.w)*x[7];
        }
        s_t1[t] = d;
    }
    __syncthreads();
    // h = w1 xq + sum_s l1s t1 ; ah = gelu(h)
    if (t < 128) {
        int q = t >> 6, e = t & 63;
        const uint4* wp = (const uint4*)(sW1B + e * 72);
        const float* xp = s_xq + q * 64;
        float acc = 0.f;
        #pragma unroll
        for (int j = 0; j < 8; ++j) {
            uint4 u = wp[j];
            const float* x = xp + j * 8;
            acc += bflo(u.x)*x[0] + bfhi(u.x)*x[1] + bflo(u.y)*x[2] + bfhi(u.y)*x[3]
                 + bflo(u.z)*x[4] + bfhi(u.z)*x[5] + bflo(u.w)*x[6] + bfhi(u.w)*x[7];
        }
        #pragma unroll
        for (int s = 0; s < 6; ++s)
            acc += bflo((unsigned)bufB[(s * 4 + 0) * 72 + e]) * s_t1[q * 6 + s];
        s_ah[t] = gelu_f(acc);
    }
    __syncthreads();
    if (t < 12) {
        int q = t / 6, s = t - q * 6;
        const uint4* rp = (const uint4*)(bufB + (s * 4 + 3) * 72);
        const float* xp = s_ah + q * 64;
        float d = 0.f;
        #pragma unroll
        for (int j = 0; j < 8; ++j) {
            uint4 u = rp[j];
            const float* x = xp + j * 8;
            d += bflo(u.x)*x[0] + bfhi(u.x)*x[1] + bflo(u.y)*x[2] + bfhi(u.y)*x[3]
               + bflo(u.z)*x[4] + bfhi(u.z)*x[5] + bflo(u.w)*x[6] + bfhi(u.w)*x[7];
        }
        s_t2[t] = d;
    }
    __syncthreads();
    if (t < 128) {
        int q = t >> 6, e = t & 63;
        const uint4* wp = (const uint4*)(sW2B + e * 72);
        const float* xp = s_ah + q * 64;
        float acc = 0.f;
        #pragma unroll
        for (int j = 0; j < 8; ++j) {
            uint4 u = wp[j];
            const float* x = xp + j * 8;
            acc += bflo(u.x)*x[0] + bfhi(u.x)*x[1] + bflo(u.y)*x[2] + bfhi(u.y)*x[3]
                 + bflo(u.z)*x[4] + bfhi(u.z)*x[5] + bflo(u.w)*x[6] + bfhi(u.w)*x[7];
        }
        #pragma unroll
        for (int s = 0; s < 6; ++s)
            acc += bflo((unsigned)bufB[(s * 4 + 2) * 72 + e]) * s_t2[q * 6 + s];
        s_yp[t] = acc;
    }
    __syncthreads();
    if (t < 4) {
        int q = t >> 1, ll = t & 1;
        const float4* ep = (const float4*)(emb + ll * 64);
        const float4* yp = (const float4*)(s_yp + q * 64);
        float d = 0.f;
        #pragma unroll
        for (int j = 0; j < 16; ++j) {
            float4 a = ep[j], x = yp[j];
            d += a.x*x.x + a.y*x.y + a.z*x.z + a.w*x.w;
        }
        s_lg[t] = d;
    }
    __syncthreads();
    if (t == 0) {
        float lsum = 0.f, corr = 0.f;
        #pragma unroll
        for (int q = 0; q < 2; ++q) {
            float l0 = s_lg[q * 2], l1 = s_lg[q * 2 + 1];
            int lab = qys[b * 2 + q];
            float m = fmaxf(l0, l1);
            float lse = m + logf(expf(l0 - m) + expf(l1 - m));
            lsum += -((lab ? l1 : l0) - lse);
            int pred = (l1 > l0) ? 1 : 0;
            corr += (pred == lab) ? 1.0f : 0.0f;
        }
        part[b] = lsum;
        part[512 + b] = corr;
    }
}

__global__ void __launch_bounds__(256) finalize_kernel(const float* __restrict__ part,
                                                       float* __restrict__ out)
{
    __shared__ float sl[256], sc[256];
    const int t = threadIdx.x;
    sl[t] = part[t] + part[t + 256];
    sc[t] = part[512 + t] + part[768 + t];
    __syncthreads();
    for (int s = 128; s > 0; s >>= 1) {
        if (t < s) { sl[t] += sl[t + s]; sc[t] += sc[t + s]; }
        __syncthreads();
    }
    if (t == 0) {
        float loss = sl[0] * (1.0f / 1024.0f);
        out[0] = loss;
        out[1] = loss;
        out[2] = 0.0f;
        out[3] = sc[0];
        out[4] = 1024.0f;
    }
}

extern "C" void kernel_launch(void* const* d_in, const int* in_sizes, int n_in,
                              void* d_out, int out_size, void* d_ws, size_t ws_size,
                              hipStream_t stream)
{
    (void)in_sizes; (void)n_in; (void)out_size; (void)ws_size;
    const float* sxs  = (const float*)d_in[1];
    const float* qxs  = (const float*)d_in[2];
    const float* c1w  = (const float*)d_in[4];
    const float* c1b  = (const float*)d_in[5];
    const float* bn1  = (const float*)d_in[6];
    const float* c2w  = (const float*)d_in[7];
    const float* c2b  = (const float*)d_in[8];
    const float* bn2  = (const float*)d_in[9];
    const float* c3w  = (const float*)d_in[10];
    const float* c3b  = (const float*)d_in[11];
    const float* bn3  = (const float*)d_in[12];
    const float* c4w  = (const float*)d_in[13];
    const float* c4b  = (const float*)d_in[14];
    const float* bn4  = (const float*)d_in[15];
    const float* lin_w= (const float*)d_in[16];
    const float* emb  = (const float*)d_in[17];
    const float* w1   = (const float*)d_in[18];
    const float* w2   = (const float*)d_in[19];
    const float* tags = (const float*)d_in[20];
    const float* rq   = (const float*)d_in[21];
    const float* rk   = (const float*)d_in[22];
    const float* rv   = (const float*)d_in[23];
    const float* ro   = (const float*)d_in[24];
    const float* lnw  = (const float*)d_in[25];
    const float* lnb  = (const float*)d_in[26];
    const int*   sys  = (const int*)d_in[27];
    const int*   qys  = (const int*)d_in[28];

    float* ws  = (float*)d_ws;
    float* out = (float*)d_out;

    precompute_kernel<<<64, 256, 0, stream>>>(c1w, c1b, bn1, c2w, c2b, bn2,
                                              c3w, c3b, bn3, c4w, c4b, bn4,
                                              w1, w2, rq, ro, ws);
    feats_kernel<<<512, 1024, 0, stream>>>(sxs, qxs, lin_w, ws, ws + WS_FEATS);
    head_kernel<<<512, 256, 0, stream>>>(emb, tags, rk, rv, lnw, lnb, sys, qys,
                                         ws, ws + WS_FEATS, ws + WS_PART);
    finalize_kernel<<<1, 256, 0, stream>>>(ws + WS_PART, out);
}

// Round 3
// 166.663 us; speedup vs baseline: 1.1229x; 1.1229x over previous
//
#include <hip/hip_runtime.h>
#include <math.h>

constexpr int NSUP = 3072;            // B*S images
constexpr float EPSF = 1e-5f;

// Workspace layout (float offsets)
constexpr int WS_W1B  = 0;            // bf16 [kt2][h2][quad4][col16][8] conv1 composite -> 1024 f
constexpr int WS_B1   = 1024;         // fp32 32
constexpr int WS_W2B  = 1056;         // bf16 [tap9][h2][quad4][col16][8] = 9216 ush = 4608 f
constexpr int WS_W3B  = 5664;         // same
constexpr int WS_W4B  = 10272;        // bf16 [tap9][ic32] = 288 ush = 144 f
constexpr int WS_B4   = 10416;        // fp32 1 (+pad)
constexpr int WS_B2   = 10420;        // fp32 32
constexpr int WS_B3   = 10452;        // fp32 32
constexpr int WS_HW1  = 10484;        // bf16 [64][72] = 4608 ush = 2304 f
constexpr int WS_HW2  = 12788;
constexpr int WS_HRQ  = 15092;
constexpr int WS_HROT = 17396;        // ro^T
constexpr int WS_RKB  = 19700;        // bf16 [4 n][16 slot][16 h], rk*0.25  (512 f)
constexpr int WS_RVT  = 20212;        // bf16 [4 n][16 h][16 slot]           (512 f)
constexpr int WS_PART = 20724;        // [512] loss, [512] correct
constexpr int WS_FEATS= 21748;        // 4096*64 f32

using short8 = __attribute__((ext_vector_type(8))) short;
using f32x4  = __attribute__((ext_vector_type(4))) float;

// Branchless gelu: 0.5x(1+erf(x/sqrt2)), erf via A&S 7.1.26 (|err|<=1.5e-7).
__device__ __forceinline__ float gelu_f(float x) {
    float z  = fabsf(x) * 0.70710678118654752440f;
    float t  = __builtin_amdgcn_rcpf(__builtin_fmaf(0.3275911f, z, 1.0f));
    float p  = t * __builtin_fmaf(t,
                 __builtin_fmaf(t,
                   __builtin_fmaf(t,
                     __builtin_fmaf(t, 1.061405429f, -1.453152027f),
                     1.421413741f),
                   -0.284496736f),
                 0.254829592f);
    float e  = __expf(-z * z);
    float er = __builtin_fmaf(-p, e, 1.0f);          // erf(|x|/sqrt2)
    float s  = copysignf(er, x);
    return 0.5f * x * (1.0f + s);
}
__device__ __forceinline__ unsigned short f2bf(float f) {
    unsigned u = __float_as_uint(f);
    return (unsigned short)((u + 0x7FFFu + ((u >> 16) & 1u)) >> 16);
}
__device__ __forceinline__ float bflo(unsigned u) { return __uint_as_float(u << 16); }
__device__ __forceinline__ float bfhi(unsigned u) { return __uint_as_float(u & 0xffff0000u); }

// ---------------------------------------------------------------------------
// Precompute: fold BN; emit bf16 MFMA layouts for all conv + head weights.
// Conv weights in [..][h][quad][col][8ch] order (contiguous per-wave fragment).
// ---------------------------------------------------------------------------
__global__ void __launch_bounds__(256) precompute_kernel(
    const float* __restrict__ c1w, const float* __restrict__ c1b, const float* __restrict__ bn1,
    const float* __restrict__ c2w, const float* __restrict__ c2b, const float* __restrict__ bn2,
    const float* __restrict__ c3w, const float* __restrict__ c3b, const float* __restrict__ bn3,
    const float* __restrict__ c4w, const float* __restrict__ c4b, const float* __restrict__ bn4,
    const float* __restrict__ w1, const float* __restrict__ w2,
    const float* __restrict__ rq, const float* __restrict__ ro,
    const float* __restrict__ rk, const float* __restrict__ rv,
    float* __restrict__ ws)
{
    const int gid = blockIdx.x * 256 + threadIdx.x;
    const int gsz = gridDim.x * 256;

    // conv1 composite B: v = (((kt*2+h)*4+qd)*16+col)*8 + c8
    unsigned short* w1b = (unsigned short*)(ws + WS_W1B);
    for (int v = gid; v < 2048; v += gsz) {
        int c8 = v & 7, colx = (v >> 3) & 15, qd = (v >> 7) & 3, hh = (v >> 9) & 1, kt = v >> 10;
        int tap = kt * 32 + qd * 8 + c8;
        int oc = hh * 16 + colx;
        unsigned short o = 0;
        if (tap < 36) {
            int tt = tap / 6, s = tap - tt * 6;
            float sum = 0.f;
            for (int di = 0; di < 3; ++di) {
                int a = tt - di; if (a < 0 || a > 3) continue;
                for (int dj = 0; dj < 3; ++dj) {
                    int bb = s - dj; if (bb < 0 || bb > 3) continue;
                    sum += c1w[oc * 9 + di * 3 + dj];
                }
            }
            float sc1 = bn1[oc] * rsqrtf(bn1[96 + oc] + EPSF);
            o = f2bf(sum * sc1 * (1.0f / 16.0f));
        }
        w1b[v] = o;
    }
    for (int c = gid; c < 32; c += gsz) {
        float sc1 = bn1[c] * rsqrtf(bn1[96 + c] + EPSF);
        ws[WS_B1 + c] = (c1b[c] - bn1[64 + c]) * sc1 + bn1[32 + c];
        float sc2 = bn2[c] * rsqrtf(bn2[96 + c] + EPSF);
        ws[WS_B2 + c] = (c2b[c] - bn2[64 + c]) * sc2 + bn2[32 + c];
        float sc3 = bn3[c] * rsqrtf(bn3[96 + c] + EPSF);
        ws[WS_B3 + c] = (c3b[c] - bn3[64 + c]) * sc3 + bn3[32 + c];
    }
    // conv2/3: v = (((tap*2+h)*4+qd)*16+col)*8 + c8 ; oc=h*16+col, ic=qd*8+c8
    unsigned short* w2b = (unsigned short*)(ws + WS_W2B);
    unsigned short* w3b = (unsigned short*)(ws + WS_W3B);
    for (int v = gid; v < 9216; v += gsz) {
        int c8 = v & 7, colx = (v >> 3) & 15, qd = (v >> 7) & 3, hh = (v >> 9) & 1, tap = v >> 10;
        int oc = hh * 16 + colx;
        int ic = qd * 8 + c8;
        float sc2 = bn2[oc] * rsqrtf(bn2[96 + oc] + EPSF);
        float sc3 = bn3[oc] * rsqrtf(bn3[96 + oc] + EPSF);
        w2b[v] = f2bf(c2w[oc * 288 + ic * 9 + tap] * sc2);
        w3b[v] = f2bf(c3w[oc * 288 + ic * 9 + tap] * sc3);
    }
    {
        unsigned short* w4b = (unsigned short*)(ws + WS_W4B);
        float sc4 = bn4[0] * rsqrtf(bn4[3] + EPSF);
        for (int v = gid; v < 288; v += gsz) {
            int tap = v >> 5, ic = v & 31;
            w4b[v] = f2bf(c4w[ic * 9 + tap] * sc4);
        }
        if (gid == 0) ws[WS_B4] = (c4b[0] - bn4[2]) * sc4 + bn4[1];
    }
    // head weights bf16 [64][72]
    unsigned short* hw1 = (unsigned short*)(ws + WS_HW1);
    unsigned short* hw2 = (unsigned short*)(ws + WS_HW2);
    unsigned short* hrq = (unsigned short*)(ws + WS_HRQ);
    unsigned short* hro = (unsigned short*)(ws + WS_HROT);
    for (int v = gid; v < 4608; v += gsz) {
        int e = v / 72, d = v - e * 72;
        unsigned short a = 0, b = 0, c = 0, r = 0;
        if (d < 64) {
            a = f2bf(w1[e * 64 + d]);
            b = f2bf(w2[e * 64 + d]);
            c = f2bf(rq[e * 64 + d]);
            r = f2bf(ro[d * 64 + e]);
        }
        hw1[v] = a; hw2[v] = b; hrq[v] = c; hro[v] = r;
    }
    // attention operand layouts: rkB[n][r][h] = rk*0.25 ; rvT[n][h][r]
    unsigned short* rkb = (unsigned short*)(ws + WS_RKB);
    unsigned short* rvt = (unsigned short*)(ws + WS_RVT);
    for (int v = gid; v < 1024; v += gsz) {
        int nn = v >> 8, x = (v >> 4) & 15, y = v & 15;
        rkb[v] = f2bf(rk[x * 64 + nn * 16 + y] * 0.25f);   // r=x, h=y
        rvt[v] = f2bf(rv[y * 64 + nn * 16 + x]);           // h=x, r=y
    }
}

// ---------------------------------------------------------------------------
// feats: BARRIER-FREE. 256 threads = 4 waves = 4 images (1 wave/image).
// Activations: wave-private LDS, chunk-major [4 ch-chunk][100 px][8 ch] bf16.
// Conv weight B-fragments read directly from global (L2-resident) -> no
// shared weight buffer -> zero __syncthreads in the whole kernel. In-wave
// LDS ordering (per-wave in-order DS pipe) covers all RAW/WAR hazards.
// ---------------------------------------------------------------------------
__device__ __forceinline__ void conv32g(const unsigned short* __restrict__ A,
                                        const unsigned short* __restrict__ Wg,
                                        int col, int quad, f32x4 (&acc)[4][2])
{
    int ab[4];
    #pragma unroll
    for (int mt = 0; mt < 4; ++mt) {
        int px = mt * 16 + col;
        ab[mt] = quad * 800 + ((px >> 3) * 10 + (px & 7)) * 8;
        acc[mt][0] = (f32x4){0,0,0,0};
        acc[mt][1] = (f32x4){0,0,0,0};
    }
    #pragma unroll
    for (int dr = 0; dr < 3; ++dr)
        #pragma unroll
        for (int dc = 0; dc < 3; ++dc) {
            int tap = dr * 3 + dc;
            short8 b0 = *(const short8*)(Wg + (((tap * 2 + 0) * 4 + quad) * 16 + col) * 8);
            short8 b1 = *(const short8*)(Wg + (((tap * 2 + 1) * 4 + quad) * 16 + col) * 8);
            #pragma unroll
            for (int mt = 0; mt < 4; ++mt) {
                short8 a = *(const short8*)(A + ab[mt] + (dr * 10 + dc) * 8);
                acc[mt][0] = __builtin_amdgcn_mfma_f32_16x16x32_bf16(a, b0, acc[mt][0], 0, 0, 0);
                acc[mt][1] = __builtin_amdgcn_mfma_f32_16x16x32_bf16(a, b1, acc[mt][1], 0, 0, 0);
            }
        }
}

__device__ __forceinline__ void conv_store4(unsigned short* __restrict__ A,
                                            const f32x4 (&acc)[4][2],
                                            float bi0, float bi1, int col, int quad)
{
    #pragma unroll
    for (int mt = 0; mt < 4; ++mt)
        #pragma unroll
        for (int reg = 0; reg < 4; ++reg) {
            int px = mt * 16 + quad * 4 + reg;
            int P = ((px >> 3) + 1) * 10 + (px & 7) + 1;
            A[(col >> 3) * 800 + P * 8 + (col & 7)]       = f2bf(gelu_f(acc[mt][0][reg] + bi0));
            A[(2 + (col >> 3)) * 800 + P * 8 + (col & 7)] = f2bf(gelu_f(acc[mt][1][reg] + bi1));
        }
}

__global__ void __launch_bounds__(256, 4) feats_kernel(
    const float* __restrict__ sxs, const float* __restrict__ qxs,
    const float* __restrict__ lin_w, const float* __restrict__ ws,
    float* __restrict__ feats)
{
    __shared__ __align__(16) unsigned short sAct[4][3200];
    __shared__ __align__(16) float sh4[4][64];

    const int t    = threadIdx.x;
    const int wv   = t >> 6;
    const int lane = t & 63;
    const int col  = lane & 15;
    const int quad = lane >> 4;
    const int n    = blockIdx.x * 4 + wv;

    unsigned short* A = sAct[wv];

    float bi1a = ws[WS_B1 + col], bi1b = ws[WS_B1 + 16 + col];
    float bi2a = ws[WS_B2 + col], bi2b = ws[WS_B2 + 16 + col];
    float bi3a = ws[WS_B3 + col], bi3b = ws[WS_B3 + 16 + col];
    float b4   = ws[WS_B4];

    // Stage this wave's image into its own act region (bf16, linear).
    {
        const float* img = (n < NSUP) ? (sxs + (size_t)n * 784) : (qxs + (size_t)(n - NSUP) * 784);
        const float4* sv = (const float4*)img;
        #pragma unroll
        for (int j = 0; j < 4; ++j) {
            int idx = j * 64 + lane;
            if (idx < 196) {
                float4 v = sv[idx];
                ushort4 o = { f2bf(v.x), f2bf(v.y), f2bf(v.z), f2bf(v.w) };
                *(ushort4*)(A + idx * 4) = o;
            }
        }
    }

    // ---- conv1: 64x32xK36 MFMA GEMM (weights from global) ----
    f32x4 acc[4][2];
    {
        const unsigned short* w1g = (const unsigned short*)(ws + WS_W1B);
        short8 b00 = *(const short8*)(w1g + ((0 * 4 + quad) * 16 + col) * 8);  // kt0 h0
        short8 b01 = *(const short8*)(w1g + ((1 * 4 + quad) * 16 + col) * 8);  // kt0 h1
        short8 b10 = *(const short8*)(w1g + ((2 * 4 + quad) * 16 + col) * 8);  // kt1 h0
        short8 b11 = *(const short8*)(w1g + ((3 * 4 + quad) * 16 + col) * 8);  // kt1 h1
        int ttj[8], ssj[8];
        #pragma unroll
        for (int j = 0; j < 8; ++j) {
            int k = quad * 8 + j;
            ttj[j] = k / 6; ssj[j] = k - ttj[j] * 6;
        }
        #pragma unroll
        for (int mt = 0; mt < 4; ++mt) {
            acc[mt][0] = (f32x4){0,0,0,0};
            acc[mt][1] = (f32x4){0,0,0,0};
            int px = mt * 16 + col;
            int sr = (((px >> 3) * 7) >> 1) - 1;
            int sc = (((px & 7) * 7) >> 1) - 1;
            short8 a0;
            #pragma unroll
            for (int j = 0; j < 8; ++j) {
                int rr = sr + ttj[j], cc = sc + ssj[j];
                bool ok = ((unsigned)rr < 28u) && ((unsigned)cc < 28u);
                int off = ok ? (rr * 28 + cc) : 0;
                unsigned short hv = A[off];
                a0[j] = ok ? (short)hv : (short)0;
            }
            acc[mt][0] = __builtin_amdgcn_mfma_f32_16x16x32_bf16(a0, b00, acc[mt][0], 0, 0, 0);
            acc[mt][1] = __builtin_amdgcn_mfma_f32_16x16x32_bf16(a0, b01, acc[mt][1], 0, 0, 0);
            short8 a1 = {0,0,0,0,0,0,0,0};
            if (quad == 0) {
                #pragma unroll
                for (int j = 0; j < 4; ++j) {          // k=32..35 -> tt=5, ss=2+j
                    int rr = sr + 5, cc = sc + 2 + j;
                    bool ok = ((unsigned)rr < 28u) && ((unsigned)cc < 28u);
                    int off = ok ? (rr * 28 + cc) : 0;
                    unsigned short hv = A[off];
                    a1[j] = ok ? (short)hv : (short)0;
                }
            }
            acc[mt][0] = __builtin_amdgcn_mfma_f32_16x16x32_bf16(a1, b10, acc[mt][0], 0, 0, 0);
            acc[mt][1] = __builtin_amdgcn_mfma_f32_16x16x32_bf16(a1, b11, acc[mt][1], 0, 0, 0);
        }
    }
    // Halo ring zero (after all img reads; same wave -> DS pipe keeps order).
    {
        uint4 z4 = {0, 0, 0, 0};
        #pragma unroll
        for (int it = 0; it < 3; ++it) {
            int h = lane + it * 64;
            if (h < 144) {                             // 36 halo pixels x 4 chunks
                int pi = h >> 2, ch = h & 3;
                int P;
                if (pi < 10)      P = pi;
                else if (pi < 20) P = 90 + (pi - 10);
                else { int k = pi - 20; int r = 1 + (k >> 1); P = r * 10 + (k & 1) * 9; }
                ((uint4*)A)[ch * 100 + P] = z4;
            }
        }
    }
    conv_store4(A, acc, bi1a, bi1b, col, quad);

    // ---- conv2 / conv3 (weights from global, in-place, wave-private) ----
    conv32g(A, (const unsigned short*)(ws + WS_W2B), col, quad, acc);
    conv_store4(A, acc, bi2a, bi2b, col, quad);
    conv32g(A, (const unsigned short*)(ws + WS_W3B), col, quad, acc);
    conv_store4(A, acc, bi3a, bi3b, col, quad);

    // ---- conv4 (32->1) via broadcast-B MFMA ----
    {
        f32x4 acc4[4];
        int ab[4];
        #pragma unroll
        for (int mt = 0; mt < 4; ++mt) {
            int px = mt * 16 + col;
            ab[mt] = quad * 800 + ((px >> 3) * 10 + (px & 7)) * 8;
            acc4[mt] = (f32x4){0,0,0,0};
        }
        const unsigned short* w4g = (const unsigned short*)(ws + WS_W4B);
        #pragma unroll
        for (int dr = 0; dr < 3; ++dr)
            #pragma unroll
            for (int dc = 0; dc < 3; ++dc) {
                int tap = dr * 3 + dc;
                short8 b = *(const short8*)(w4g + tap * 32 + quad * 8);
                #pragma unroll
                for (int mt = 0; mt < 4; ++mt) {
                    short8 a = *(const short8*)(A + ab[mt] + (dr * 10 + dc) * 8);
                    acc4[mt] = __builtin_amdgcn_mfma_f32_16x16x32_bf16(a, b, acc4[mt], 0, 0, 0);
                }
            }
        if (col < 4) {
            f32x4 v = acc4[0];
            if (col == 1) v = acc4[1];
            else if (col == 2) v = acc4[2];
            else if (col == 3) v = acc4[3];
            #pragma unroll
            for (int reg = 0; reg < 4; ++reg)
                sh4[wv][col * 16 + quad * 4 + reg] = gelu_f(v[reg] + b4);
        }
    }

    // ---- Linear 64x64 fp32 (sh4 wave-private; in-wave DS order suffices) ----
    {
        const float4* lw = (const float4*)(lin_w + (size_t)lane * 64);
        const float4* hp = (const float4*)sh4[wv];
        float acc2 = 0.f;
        #pragma unroll
        for (int j = 0; j < 16; ++j) {
            float4 w = lw[j], h = hp[j];
            acc2 += w.x * h.x + w.y * h.y + w.z * h.z + w.w * h.w;
        }
        feats[n * 64 + lane] = acc2;
    }
}

// ---------------------------------------------------------------------------
// head: 1 batch element per block, 256 threads, bf16 MFMA GEMMs.
// Attention is now MFMA per head-wave; reductions widened via shfl.
// ---------------------------------------------------------------------------
__device__ __forceinline__ void head_gemm(const unsigned short* __restrict__ Ab,
                                          const unsigned short* __restrict__ Bw,
                                          int col, int quad, int wvid, f32x4 res[2])
{
    #pragma unroll
    for (int u = 0; u < 2; ++u) {
        int tau = wvid + u * 4;
        int mt = tau & 1, nt = tau >> 1;
        f32x4 acc = {0, 0, 0, 0};
        #pragma unroll
        for (int kt = 0; kt < 2; ++kt) {
            short8 a = *(const short8*)(Ab + (mt * 16 + col) * 72 + kt * 32 + quad * 8);
            short8 b = *(const short8*)(Bw + (nt * 16 + col) * 72 + kt * 32 + quad * 8);
            acc = __builtin_amdgcn_mfma_f32_16x16x32_bf16(a, b, acc, 0, 0, 0);
        }
        res[u] = acc;
    }
}

__global__ void __launch_bounds__(256, 2) head_kernel(
    const float* __restrict__ emb, const float* __restrict__ tags,
    const float* __restrict__ lnw, const float* __restrict__ lnb,
    const int* __restrict__ sys, const int* __restrict__ qys,
    const float* __restrict__ ws, const float* __restrict__ feats,
    float* __restrict__ part)
{
    __shared__ __align__(16) unsigned short sW1B[4608], sW2B[4608], sRQB[4608], sROT[4608];
    __shared__ __align__(16) unsigned short bufA[2304], bufB[2304];
    __shared__ __align__(16) unsigned short sP[2048];          // [32 tok][64 (n,slot)]
    __shared__ __align__(16) float sXf[1536];
    __shared__ __align__(16) float s_xq[128], s_ah[128], s_yp[128];
    __shared__ float s_t1[12], s_t2[12], s_mu[24], s_rs[24], s_lg[4];

    const int t    = threadIdx.x;
    const int b    = blockIdx.x;
    const int wvid = t >> 6;
    const int col  = t & 15;
    const int quad = (t >> 4) & 3;

    for (int i = t; i < 576; i += 256) {      // 4608 ush = 576 uint4 each
        ((uint4*)sW1B)[i] = ((const uint4*)(ws + WS_HW1))[i];
        ((uint4*)sW2B)[i] = ((const uint4*)(ws + WS_HW2))[i];
        ((uint4*)sRQB)[i] = ((const uint4*)(ws + WS_HRQ))[i];
        ((uint4*)sROT)[i] = ((const uint4*)(ws + WS_HROT))[i];
    }
    {
        uint4 z = {0, 0, 0, 0};
        if (t < 72) {   // zero pad rows 24..31 of bufA/bufB
            ((uint4*)(bufA + 1728))[t] = z;
            ((uint4*)(bufB + 1728))[t] = z;
        }
        if (t < 64)     // zero rows 24..31 of sP
            ((uint4*)(sP + 1536))[t] = z;
    }
    // tokens (fp32 + bf16)
    for (int idx = t; idx < 1536; idx += 256) {
        int k = idx >> 6, e = idx & 63;
        int s = k >> 2, tg = k & 3;
        int cls = sys[b * 6 + s];
        float v = feats[(b * 6 + s) * 64 + e] + emb[cls * 64 + e] + tags[tg * 64 + e];
        sXf[idx] = v;
        bufA[k * 72 + e] = f2bf(v);
    }
    __syncthreads();

    f32x4 r[2];
    // GEMM1: ah = gelu(X @ w1^T) -> bufB
    head_gemm(bufA, sW1B, col, quad, wvid, r);
    #pragma unroll
    for (int u = 0; u < 2; ++u) {
        int tau = wvid + u * 4, mt = tau & 1, nt = tau >> 1;
        #pragma unroll
        for (int reg = 0; reg < 4; ++reg) {
            int row = mt * 16 + quad * 4 + reg;
            if (row < 24) bufB[row * 72 + nt * 16 + col] = f2bf(gelu_f(r[u][reg]));
        }
    }
    __syncthreads();
    // GEMM2: q = ah @ w2^T -> bufA
    head_gemm(bufB, sW2B, col, quad, wvid, r);
    #pragma unroll
    for (int u = 0; u < 2; ++u) {
        int tau = wvid + u * 4, mt = tau & 1, nt = tau >> 1;
        #pragma unroll
        for (int reg = 0; reg < 4; ++reg) {
            int row = mt * 16 + quad * 4 + reg;
            if (row < 24) bufA[row * 72 + nt * 16 + col] = f2bf(r[u][reg]);
        }
    }
    __syncthreads();
    // GEMM3: qh = q @ rq^T -> bufB
    head_gemm(bufA, sRQB, col, quad, wvid, r);
    #pragma unroll
    for (int u = 0; u < 2; ++u) {
        int tau = wvid + u * 4, mt = tau & 1, nt = tau >> 1;
        #pragma unroll
        for (int reg = 0; reg < 4; ++reg) {
            int row = mt * 16 + quad * 4 + reg;
            if (row < 24) bufB[row * 72 + nt * 16 + col] = f2bf(r[u][reg]);
        }
    }
    __syncthreads();

    // ---- attention via MFMA: wave = head. QK^T -> row softmax -> PV ----
    {
        const int nh = wvid;
        const unsigned short* rkB = (const unsigned short*)(ws + WS_RKB) + nh * 256;
        const unsigned short* rvT = (const unsigned short*)(ws + WS_RVT) + nh * 256;
        const short8 zz = {0,0,0,0,0,0,0,0};
        const bool lo = (quad < 2);
        // S[tok][slot] = qh . (rk*0.25): A rows=tok (k=h), B cols=slot (k=h)
        short8 bK = lo ? *(const short8*)(rkB + col * 16 + quad * 8) : zz;
        short8 a0 = lo ? *(const short8*)(bufB + col * 72 + nh * 16 + quad * 8) : zz;
        short8 a1 = lo ? *(const short8*)(bufB + (16 + col) * 72 + nh * 16 + quad * 8) : zz;
        f32x4 s0 = __builtin_amdgcn_mfma_f32_16x16x32_bf16(a0, bK, (f32x4){0,0,0,0}, 0, 0, 0);
        f32x4 s1 = __builtin_amdgcn_mfma_f32_16x16x32_bf16(a1, bK, (f32x4){0,0,0,0}, 0, 0, 0);
        // softmax per row (across the 16 col-lanes = slots); store P bf16
        #pragma unroll
        for (int reg = 0; reg < 4; ++reg) {
            float v = s0[reg];
            float m = v;
            m = fmaxf(m, __shfl_xor(m, 1)); m = fmaxf(m, __shfl_xor(m, 2));
            m = fmaxf(m, __shfl_xor(m, 4)); m = fmaxf(m, __shfl_xor(m, 8));
            float p = __expf(v - m);
            float su = p;
            su += __shfl_xor(su, 1); su += __shfl_xor(su, 2);
            su += __shfl_xor(su, 4); su += __shfl_xor(su, 8);
            sP[(quad * 4 + reg) * 64 + nh * 16 + col] = f2bf(p / su);
            v = s1[reg];
            m = v;
            m = fmaxf(m, __shfl_xor(m, 1)); m = fmaxf(m, __shfl_xor(m, 2));
            m = fmaxf(m, __shfl_xor(m, 4)); m = fmaxf(m, __shfl_xor(m, 8));
            p = __expf(v - m);
            su = p;
            su += __shfl_xor(su, 1); su += __shfl_xor(su, 2);
            su += __shfl_xor(su, 4); su += __shfl_xor(su, 8);
            if (quad < 2) sP[(16 + quad * 4 + reg) * 64 + nh * 16 + col] = f2bf(p / su);
        }
        // PV: O[tok][h] = P @ rv  (A rows=tok k=slot, B cols=h k=slot)
        short8 bV  = lo ? *(const short8*)(rvT + col * 16 + quad * 8) : zz;
        short8 pa0 = lo ? *(const short8*)(sP + col * 64 + nh * 16 + quad * 8) : zz;
        short8 pa1 = lo ? *(const short8*)(sP + (16 + col) * 64 + nh * 16 + quad * 8) : zz;
        f32x4 o0 = __builtin_amdgcn_mfma_f32_16x16x32_bf16(pa0, bV, (f32x4){0,0,0,0}, 0, 0, 0);
        f32x4 o1 = __builtin_amdgcn_mfma_f32_16x16x32_bf16(pa1, bV, (f32x4){0,0,0,0}, 0, 0, 0);
        #pragma unroll
        for (int reg = 0; reg < 4; ++reg) {
            bufA[(quad * 4 + reg) * 72 + nh * 16 + col] = f2bf(o0[reg]);
            int tok = 16 + quad * 4 + reg;
            if (tok < 24) bufA[tok * 72 + nh * 16 + col] = f2bf(o1[reg]);
        }
    }
    __syncthreads();

    // GEMM4: z = x + lor @ ro -> sXf (in-place)
    head_gemm(bufA, sROT, col, quad, wvid, r);
    #pragma unroll
    for (int u = 0; u < 2; ++u) {
        int tau = wvid + u * 4, mt = tau & 1, nt = tau >> 1;
        #pragma unroll
        for (int reg = 0; reg < 4; ++reg) {
            int row = mt * 16 + quad * 4 + reg;
            if (row < 24) {
                int idx = row * 64 + nt * 16 + col;
                sXf[idx] = sXf[idx] + r[u][reg];
            }
        }
    }
    __syncthreads();

    // LayerNorm stats (widened: 24 tokens x 8 lanes, shfl width-8 reduce)
    if (t < 192) {
        int k = t >> 3, j = t & 7;
        const float4* zp = (const float4*)(sXf + k * 64 + j * 8);
        float4 v0 = zp[0], v1 = zp[1];
        float sx_ = v0.x + v0.y + v0.z + v0.w + v1.x + v1.y + v1.z + v1.w;
        sx_ += __shfl_xor(sx_, 1); sx_ += __shfl_xor(sx_, 2); sx_ += __shfl_xor(sx_, 4);
        float mu = sx_ * (1.0f / 64.0f);
        float d0 = v0.x - mu, d1 = v0.y - mu, d2 = v0.z - mu, d3 = v0.w - mu;
        float d4 = v1.x - mu, d5 = v1.y - mu, d6 = v1.z - mu, d7 = v1.w - mu;
        float vv = d0*d0 + d1*d1 + d2*d2 + d3*d3 + d4*d4 + d5*d5 + d6*d6 + d7*d7;
        vv += __shfl_xor(vv, 1); vv += __shfl_xor(vv, 2); vv += __shfl_xor(vv, 4);
        if (j == 0) {
            s_mu[k] = mu;
            s_rs[k] = 1.0f / sqrtf(vv * (1.0f / 64.0f) + EPSF);
        }
    }
    __syncthreads();
    // normalize -> lors bf16 in bufB ; xq staged in parallel
    for (int idx = t; idx < 1536; idx += 256) {
        int k = idx >> 6, e = idx & 63;
        float v = (sXf[idx] - s_mu[k]) * s_rs[k] * lnw[e] + lnb[e];
        bufB[k * 72 + e] = f2bf(v);
    }
    if (t < 128) {
        int q = t >> 6, e = t & 63;
        s_xq[t] = feats[(NSUP + b * 2 + q) * 64 + e] + tags[256 + e];
    }
    __syncthreads();

    // t1[q][s] = r1s[s] . xq[q]   (12 dots x 8 lanes)
    if (t < 96) {
        int idx = t >> 3, j = t & 7;
        int q = idx / 6, s = idx - q * 6;
        uint4 u = ((const uint4*)(bufB + (s * 4 + 1) * 72))[j];
        const float* x = s_xq + q * 64 + j * 8;
        float d = bflo(u.x)*x[0] + bfhi(u.x)*x[1] + bflo(u.y)*x[2] + bfhi(u.y)*x[3]
                + bflo(u.z)*x[4] + bfhi(u.z)*x[5] + bflo(u.w)*x[6] + bfhi(u.w)*x[7];
        d += __shfl_xor(d, 1); d += __shfl_xor(d, 2); d += __shfl_xor(d, 4);
        if (j == 0) s_t1[idx] = d;
    }
    __syncthreads();
    // h = w1 xq + sum_s l1s t1 ; ah = gelu(h)
    if (t < 128) {
        int q = t >> 6, e = t & 63;
        const uint4* wp = (const uint4*)(sW1B + e * 72);
        const float* xp = s_xq + q * 64;
        float acc = 0.f;
        #pragma unroll
        for (int j = 0; j < 8; ++j) {
            uint4 u = wp[j];
            const float* x = xp + j * 8;
            acc += bflo(u.x)*x[0] + bfhi(u.x)*x[1] + bflo(u.y)*x[2] + bfhi(u.y)*x[3]
                 + bflo(u.z)*x[4] + bfhi(u.z)*x[5] + bflo(u.w)*x[6] + bfhi(u.w)*x[7];
        }
        #pragma unroll
        for (int s = 0; s < 6; ++s)
            acc += bflo((unsigned)bufB[(s * 4 + 0) * 72 + e]) * s_t1[q * 6 + s];
        s_ah[t] = gelu_f(acc);
    }
    __syncthreads();
    if (t < 96) {
        int idx = t >> 3, j = t & 7;
        int q = idx / 6, s = idx - q * 6;
        uint4 u = ((const uint4*)(bufB + (s * 4 + 3) * 72))[j];
        const float* x = s_ah + q * 64 + j * 8;
        float d = bflo(u.x)*x[0] + bfhi(u.x)*x[1] + bflo(u.y)*x[2] + bfhi(u.y)*x[3]
                + bflo(u.z)*x[4] + bfhi(u.z)*x[5] + bflo(u.w)*x[6] + bfhi(u.w)*x[7];
        d += __shfl_xor(d, 1); d += __shfl_xor(d, 2); d += __shfl_xor(d, 4);
        if (j == 0) s_t2[idx] = d;
    }
    __syncthreads();
    if (t < 128) {
        int q = t >> 6, e = t & 63;
        const uint4* wp = (const uint4*)(sW2B + e * 72);
        const float* xp = s_ah + q * 64;
        float acc = 0.f;
        #pragma unroll
        for (int j = 0; j < 8; ++j) {
            uint4 u = wp[j];
            const float* x = xp + j * 8;
            acc += bflo(u.x)*x[0] + bfhi(u.x)*x[1] + bflo(u.y)*x[2] + bfhi(u.y)*x[3]
                 + bflo(u.z)*x[4] + bfhi(u.z)*x[5] + bflo(u.w)*x[6] + bfhi(u.w)*x[7];
        }
        #pragma unroll
        for (int s = 0; s < 6; ++s)
            acc += bflo((unsigned)bufB[(s * 4 + 2) * 72 + e]) * s_t2[q * 6 + s];
        s_yp[t] = acc;
    }
    __syncthreads();
    // logits (4 dots x 8 lanes)
    if (t < 32) {
        int q = t >> 4, ll = (t >> 3) & 1, j = t & 7;
        const float* ep = emb + ll * 64 + j * 8;
        const float* yp = s_yp + q * 64 + j * 8;
        float d = ep[0]*yp[0] + ep[1]*yp[1] + ep[2]*yp[2] + ep[3]*yp[3]
                + ep[4]*yp[4] + ep[5]*yp[5] + ep[6]*yp[6] + ep[7]*yp[7];
        d += __shfl_xor(d, 1); d += __shfl_xor(d, 2); d += __shfl_xor(d, 4);
        if (j == 0) s_lg[q * 2 + ll] = d;
    }
    __syncthreads();
    if (t == 0) {
        float lsum = 0.f, corr = 0.f;
        #pragma unroll
        for (int q = 0; q < 2; ++q) {
            float l0 = s_lg[q * 2], l1 = s_lg[q * 2 + 1];
            int lab = qys[b * 2 + q];
            float m = fmaxf(l0, l1);
            float lse = m + logf(expf(l0 - m) + expf(l1 - m));
            lsum += -((lab ? l1 : l0) - lse);
            int pred = (l1 > l0) ? 1 : 0;
            corr += (pred == lab) ? 1.0f : 0.0f;
        }
        part[b] = lsum;
        part[512 + b] = corr;
    }
}

__global__ void __launch_bounds__(256) finalize_kernel(const float* __restrict__ part,
                                                       float* __restrict__ out)
{
    __shared__ float sl[256], sc[256];
    const int t = threadIdx.x;
    sl[t] = part[t] + part[t + 256];
    sc[t] = part[512 + t] + part[768 + t];
    __syncthreads();
    for (int s = 128; s > 0; s >>= 1) {
        if (t < s) { sl[t] += sl[t + s]; sc[t] += sc[t + s]; }
        __syncthreads();
    }
    if (t == 0) {
        float loss = sl[0] * (1.0f / 1024.0f);
        out[0] = loss;
        out[1] = loss;
        out[2] = 0.0f;
        out[3] = sc[0];
        out[4] = 1024.0f;
    }
}

extern "C" void kernel_launch(void* const* d_in, const int* in_sizes, int n_in,
                              void* d_out, int out_size, void* d_ws, size_t ws_size,
                              hipStream_t stream)
{
    (void)in_sizes; (void)n_in; (void)out_size; (void)ws_size;
    const float* sxs  = (const float*)d_in[1];
    const float* qxs  = (const float*)d_in[2];
    const float* c1w  = (const float*)d_in[4];
    const float* c1b  = (const float*)d_in[5];
    const float* bn1  = (const float*)d_in[6];
    const float* c2w  = (const float*)d_in[7];
    const float* c2b  = (const float*)d_in[8];
    const float* bn2  = (const float*)d_in[9];
    const float* c3w  = (const float*)d_in[10];
    const float* c3b  = (const float*)d_in[11];
    const float* bn3  = (const float*)d_in[12];
    const float* c4w  = (const float*)d_in[13];
    const float* c4b  = (const float*)d_in[14];
    const float* bn4  = (const float*)d_in[15];
    const float* lin_w= (const float*)d_in[16];
    const float* emb  = (const float*)d_in[17];
    const float* w1   = (const float*)d_in[18];
    const float* w2   = (const float*)d_in[19];
    const float* tags = (const float*)d_in[20];
    const float* rq   = (const float*)d_in[21];
    const float* rk   = (const float*)d_in[22];
    const float* rv   = (const float*)d_in[23];
    const float* ro   = (const float*)d_in[24];
    const float* lnw  = (const float*)d_in[25];
    const float* lnb  = (const float*)d_in[26];
    const int*   sys  = (const int*)d_in[27];
    const int*   qys  = (const int*)d_in[28];

    float* ws  = (float*)d_ws;
    float* out = (float*)d_out;

    precompute_kernel<<<64, 256, 0, stream>>>(c1w, c1b, bn1, c2w, c2b, bn2,
                                              c3w, c3b, bn3, c4w, c4b, bn4,
                                              w1, w2, rq, ro, rk, rv, ws);
    feats_kernel<<<1024, 256, 0, stream>>>(sxs, qxs, lin_w, ws, ws + WS_FEATS);
    head_kernel<<<512, 256, 0, stream>>>(emb, tags, lnw, lnb, sys, qys,
                                         ws, ws + WS_FEATS, ws + WS_PART);
    finalize_kernel<<<1, 256, 0, stream>>>(ws + WS_PART, out);
}